// Round 3
// baseline (487.340 us; speedup 1.0000x reference)
//
#include <hip/hip_runtime.h>
#include <hip/hip_cooperative_groups.h>
#include <math.h>

namespace cg = cooperative_groups;

#define NBATCH 2
#define HH 1024
#define WW 1024
#define KKER 24
#define KDIM 35
#define NPIX (HH*WW)
#define KSQ (KDIM*KDIM)          // 1225
#define NDA 69                   // da in [-34,34]
#define NTAU 9                   // dai tiles of 8 (last has 5)
#define NFR 18                   // stored row freqs m=0..17 (Hermitian half)
#define VCOLS 43                 // X cols 0..34 valid, 35..42 zero pad
#define GRID 512
#define TPB 256

// ---- workspace layout (float offsets) ----
#define G_OFF 0                                  // [n][y][m] complex: 2*1024*18
#define S_OFF (G_OFF + NBATCH*HH*NFR*2)          // [n][a][mb] complex half-plane
#define V_OFF (S_OFF + NBATCH*KDIM*NFR*2)        // [nb][dai][db] complex
#define V_FLOATS (NBATCH*2*NDA*KDIM*2)           // 19320

__device__ __forceinline__ float2 cmadd(float2 p, float2 w, float2 u) {
    return make_float2(fmaf(p.x, w.x, fmaf(-p.y, w.y, u.x)),
                       fmaf(p.x, w.y, fmaf( p.y, w.x, u.y)));
}
__device__ __forceinline__ float sigm(float v) {
    return 1.f / (1.f + expf(-v));
}

struct SMem {
    union {
        struct { float vs[1024]; float row[1024]; float2 P[256]; } p1;
        struct { float2 Xp[KDIM * VCOLS]; } p3;
        struct { float2 Vl[NDA * KDIM]; float2 Ul[8][KDIM]; } p4;
    } u;
    float2 twl[1024];    // persistent across phases (outside the union)
};

__device__ __forceinline__ void gen_twl(SMem& sm, int t) {
    for (int j = t; j < 1024; j += TPB) {
        float s, c;
        sincospif(-2.0f * (float)j * (1.0f / 1024.0f), &s, &c);
        sm.twl[j] = make_float2(c, s);     // e^{-2 pi i j / 1024}
    }
}

// ---- phase 1: avepool3 + sigmoid + row DFT (m=0..17), rows strided over grid ----
__device__ void phase1(SMem& sm, const float* __restrict__ mt, float* __restrict__ ws,
                       int bid, int stride, int t) {
    if (bid >= stride - 8) {                 // zero V for phase-3 atomics
        int sl = bid - (stride - 8);
        const int chunk = V_FLOATS / 8;      // 2415
        for (int i = sl * chunk + t; i < (sl + 1) * chunk; i += TPB)
            ws[V_OFF + i] = 0.f;
    }
    for (int r = bid; r < NBATCH * HH; r += stride) {
        int n = r >> 10, y = r & 1023;
        const float* base = mt + (size_t)n * NPIX;
        __syncthreads();
        {
            float4 a = ((const float4*)(base + (size_t)y * WW))[t];
            if (y > 0)    { float4 b = ((const float4*)(base + (size_t)(y - 1) * WW))[t];
                            a.x += b.x; a.y += b.y; a.z += b.z; a.w += b.w; }
            if (y < 1023) { float4 b = ((const float4*)(base + (size_t)(y + 1) * WW))[t];
                            a.x += b.x; a.y += b.y; a.z += b.z; a.w += b.w; }
            ((float4*)sm.u.p1.vs)[t] = a;
        }
        __syncthreads();
        for (int x = t; x < 1024; x += TPB) {
            float s = sm.u.p1.vs[x];
            if (x > 0)    s += sm.u.p1.vs[x - 1];
            if (x < 1023) s += sm.u.p1.vs[x + 1];
            sm.u.p1.row[x] = sigm(4.0f * (s * (1.0f / 9.0f) - 0.5f));
        }
        __syncthreads();
        if (t < 14 * NFR) {
            int g = t / NFR, m = t - NFR * g;        // 14 x-chunks of 73/74
            int xs = (g << 10) / 14, xe = ((g + 1) << 10) / 14;
            float2 cm = sm.twl[m];
            float ar = 0.f, ai = 0.f;
            for (int x0 = xs; x0 < xe; x0 += 32) {   // resync every 32 (accuracy)
                float2 wv = sm.twl[((unsigned)(m * x0)) & 1023u];
                float wr = wv.x, wi = wv.y;
                int xl = (x0 + 32 < xe) ? x0 + 32 : xe;
                for (int x = x0; x < xl; ++x) {
                    float val = sm.u.p1.row[x];
                    ar = fmaf(val, wr, ar);
                    ai = fmaf(val, wi, ai);
                    float nwr = fmaf(wr, cm.x, -wi * cm.y);
                    float nwi = fmaf(wr, cm.y,  wi * cm.x);
                    wr = nwr; wi = nwi;
                }
            }
            sm.u.p1.P[t] = make_float2(ar, ai);
        }
        __syncthreads();
        if (t < NFR) {
            float gr = 0.f, gi = 0.f;
            #pragma unroll
            for (int g = 0; g < 14; ++g) {
                gr += sm.u.p1.P[g * NFR + t].x;
                gi += sm.u.p1.P[g * NFR + t].y;
            }
            float2* Gp = (float2*)(ws + G_OFF) + (size_t)(n * HH + y) * NFR + t;
            *Gp = make_float2(gr, gi);
        }
    }
}

// ---- phase 2: column DFT -> half-plane spec S[n][a][mb], 70 active blocks ----
__device__ void phase2(SMem& sm, float* __restrict__ ws, int bid, int t) {
    if (bid >= NBATCH * KDIM) return;
    int n = bid / KDIM, a = bid - n * KDIM;
    __syncthreads();
    if (t < 14 * NFR) {
        int g = t / NFR, mb = t - NFR * g;
        int ys = (g << 10) / 14, ye = ((g + 1) << 10) / 14;
        int ma = a - 17;
        const float2* Gp = (const float2*)(ws + G_OFF) + (size_t)n * HH * NFR + mb;
        float ar = 0.f, ai = 0.f;
        for (int y = ys; y < ye; ++y) {
            float2 g2 = Gp[(size_t)y * NFR];
            float2 cc = sm.twl[((unsigned)(ma * y)) & 1023u];
            ar = fmaf(g2.x, cc.x, ar); ar = fmaf(-g2.y, cc.y, ar);
            ai = fmaf(g2.x, cc.y, ai); ai = fmaf( g2.y, cc.x, ai);
        }
        sm.u.p1.P[t] = make_float2(ar, ai);
    }
    __syncthreads();
    if (t < NFR) {
        float sr = 0.f, si = 0.f;
        #pragma unroll
        for (int g = 0; g < 14; ++g) { sr += sm.u.p1.P[g * NFR + t].x; si += sm.u.p1.P[g * NFR + t].y; }
        ((float2*)(ws + S_OFF))[(size_t)(n * KDIM + a) * NFR + t] = make_float2(sr, si);
    }
}

// ---- phase 3: autocorr tiles, atomicAdd partials into V ----
__device__ void phase3(SMem& sm, float* __restrict__ ws,
        const float* __restrict__ kfr, const float* __restrict__ kfi,
        const float* __restrict__ kdr, const float* __restrict__ kdi,
        const float* __restrict__ kfs, const float* __restrict__ kds,
        int bid, int stride, int t) {
    for (int i = t; i < KDIM * 8; i += TPB) {        // zero pad cols 35..42 once
        int a = i >> 3, c = KDIM + (i & 7);
        sm.u.p3.Xp[a * VCOLS + c] = make_float2(0.f, 0.f);
    }
    // task = tau*96 + nb*24 + k  (tau-major: stride-512 pairing balances passes)
    for (int task = bid; task < 4 * KKER * NTAU; task += stride) {
        int tau = task / 96; int rem = task - tau * 96;
        int nb = rem / KKER; int k = rem - nb * KKER;
        int br = nb & 1, n = nb >> 1;
        __syncthreads();                              // protect prior task's Xp reads
        const float* kr = (br ? kdr : kfr) + (size_t)k * KSQ;
        const float* ki = (br ? kdi : kfi) + (size_t)k * KSQ;
        const float2* Sp = (const float2*)(ws + S_OFF) + (size_t)n * KDIM * NFR;
        for (int i = t; i < KSQ; i += TPB) {
            int a = i / KDIM, b = i - a * KDIM;
            float2 s2;
            if (b >= 17) s2 = Sp[a * NFR + (b - 17)];
            else { float2 q = Sp[(34 - a) * NFR + (17 - b)]; s2 = make_float2(q.x, -q.y); }
            float krr = kr[i], kii = ki[i];
            sm.u.p3.Xp[a * VCOLS + b] =
                make_float2(s2.x * krr - s2.y * kii, s2.x * kii + s2.y * krr);
        }
        __syncthreads();
        float s = (br ? kds[k] * (0.98f * 0.98f) : kfs[k]) * 0x1p-40f;
        int wv = t >> 6, lane = t & 63;
        int apSlot = lane & 7, dai8 = lane >> 3;
        int dai = tau * 8 + dai8, da = dai - 34;
        int daiHi = tau * 8 + 7; if (daiHi > NDA - 1) daiHi = NDA - 1;
        int apLo = -(daiHi - 34); if (apLo < 0) apLo = 0;
        int apHi = KDIM - (tau * 8 - 34); if (apHi > KDIM) apHi = KDIM;
        int oct = (wv + task) & 3;                    // rotate octet->wave binding
        int npass = (oct == 3) ? 2 : 1;               // lightest wave takes db 32..34
        bool lv = (dai < NDA);
        for (int p = 0; p < npass; ++p) {
            int db0 = p ? 32 : oct * 8;
            int nbp = KDIM - db0;                     // wave-uniform
            float2 acc[8];
            #pragma unroll
            for (int j = 0; j < 8; ++j) acc[j] = make_float2(0.f, 0.f);
            for (int ap = apLo + apSlot; ap < apHi; ap += 8) {
                if (lv && ((unsigned)(ap + da) < (unsigned)KDIM)) {
                    const float2* rx = sm.u.p3.Xp + (ap + da) * VCOLS + db0;
                    const float2* ry = sm.u.p3.Xp + ap * VCOLS;
                    float2 w[8];
                    #pragma unroll
                    for (int j = 0; j < 8; ++j) w[j] = rx[j];
                    int bp = 0;
                    for (; bp + 8 <= nbp; bp += 8) {
                        #pragma unroll
                        for (int u = 0; u < 8; ++u) {
                            float2 yv = ry[bp + u];
                            #pragma unroll
                            for (int j = 0; j < 8; ++j) {
                                acc[j].x = fmaf(w[j].x, yv.x, acc[j].x);
                                acc[j].x = fmaf(w[j].y, yv.y, acc[j].x);
                                acc[j].y = fmaf(w[j].y, yv.x, acc[j].y);
                                acc[j].y = fmaf(-w[j].x, yv.y, acc[j].y);
                            }
                            #pragma unroll
                            for (int j = 0; j < 7; ++j) w[j] = w[j + 1];
                            w[7] = rx[bp + u + 8];
                        }
                    }
                    for (; bp < nbp; ++bp) {
                        float2 yv = ry[bp];
                        #pragma unroll
                        for (int j = 0; j < 8; ++j) {
                            acc[j].x = fmaf(w[j].x, yv.x, acc[j].x);
                            acc[j].x = fmaf(w[j].y, yv.y, acc[j].x);
                            acc[j].y = fmaf(w[j].y, yv.x, acc[j].y);
                            acc[j].y = fmaf(-w[j].x, yv.y, acc[j].y);
                        }
                        #pragma unroll
                        for (int j = 0; j < 7; ++j) w[j] = w[j + 1];
                        w[7] = rx[bp + 8];
                    }
                }
            }
            #pragma unroll
            for (int j = 0; j < 8; ++j) {             // reduce 8 apSlots
                acc[j].x += __shfl_xor(acc[j].x, 1); acc[j].y += __shfl_xor(acc[j].y, 1);
                acc[j].x += __shfl_xor(acc[j].x, 2); acc[j].y += __shfl_xor(acc[j].y, 2);
                acc[j].x += __shfl_xor(acc[j].x, 4); acc[j].y += __shfl_xor(acc[j].y, 4);
            }
            if (apSlot == 0 && lv) {
                float* vb = ws + V_OFF + (((size_t)nb * NDA + dai) * KDIM + db0) * 2;
                #pragma unroll
                for (int j = 0; j < 8; ++j) if (db0 + j < KDIM) {
                    atomicAdd(vb + 2 * j,     s * acc[j].x);
                    atomicAdd(vb + 2 * j + 1, s * acc[j].y);
                }
            }
        }
    }
}

// ---- phase 4: U DFT (8 rows/block) + radix-4 epilogue + stores ----
__device__ void phase4(SMem& sm, const float* __restrict__ ws, float* __restrict__ out,
                       int bid, int t) {
    int nb = bid >> 7, yc = bid & 127;
    int y0 = yc * 8;
    const float2* Vg = (const float2*)(ws + V_OFF) + (size_t)nb * NDA * KDIM;
    for (int i = t; i < NDA * KDIM; i += TPB) sm.u.p4.Vl[i] = Vg[i];
    __syncthreads();
    for (int task = t; task < 8 * KDIM; task += TPB) {
        int yl = task / KDIM, db = task - KDIM * yl;
        int y = y0 + yl;
        float ar = 0.f, ai = 0.f;
        for (int dai = 0; dai < NDA; ++dai) {
            float2 cc = sm.twl[((unsigned)(y * (dai - 34))) & 1023u];
            float cr = cc.x, ci = -cc.y;              // e^{+2pi i y da/1024}
            float2 v = sm.u.p4.Vl[dai * KDIM + db];
            ar = fmaf(v.x, cr, ar); ar = fmaf(-v.y, ci, ar);
            ai = fmaf(v.x, ci, ai); ai = fmaf( v.y, cr, ai);
        }
        sm.u.p4.Ul[yl][db] = make_float2(ar, ai);
    }
    __syncthreads();
    int n = nb >> 1, br = nb & 1;
    float2 z  = sm.twl[t];              z.y  = -z.y;
    float2 z2 = sm.twl[(2 * t) & 1023]; z2.y = -z2.y;
    float2 z3 = sm.twl[(3 * t) & 1023]; z3.y = -z3.y;
    float2 w  = sm.twl[(4 * t) & 1023]; w.y  = -w.y;  // z^4
    const size_t OS = (size_t)NBATCH * NPIX;
    #pragma unroll
    for (int yl = 0; yl < 8; ++yl) {
        int y = y0 + yl;
        float2 P0 = sm.u.p4.Ul[yl][32], P1 = sm.u.p4.Ul[yl][33];
        float2 P2 = sm.u.p4.Ul[yl][34], P3 = make_float2(0.f, 0.f);
        #pragma unroll
        for (int q = 7; q >= 0; --q) {
            P0 = cmadd(P0, w, sm.u.p4.Ul[yl][4 * q]);
            P1 = cmadd(P1, w, sm.u.p4.Ul[yl][4 * q + 1]);
            P2 = cmadd(P2, w, sm.u.p4.Ul[yl][4 * q + 2]);
            P3 = cmadd(P3, w, sm.u.p4.Ul[yl][4 * q + 3]);
        }
        float U0r = sm.u.p4.Ul[yl][0].x;
        float A1x = P1.x * z.x  - P1.y * z.y,  A1y = P1.x * z.y  + P1.y * z.x;
        float A2x = P2.x * z2.x - P2.y * z2.y;
        float A3x = P3.x * z3.x - P3.y * z3.y, A3y = P3.x * z3.y + P3.y * z3.x;
        float Re4[4];
        Re4[0] = P0.x + A1x + A2x + A3x;
        Re4[1] = P0.x - A1y - A2x + A3y;
        Re4[2] = P0.x - A1x + A2x - A3x;
        Re4[3] = P0.x + A1y - A2x - A3y;
        size_t obase = (size_t)n * NPIX + (size_t)y * WW;
        if (br == 0) {
            #pragma unroll
            for (int c = 0; c < 4; ++c) {
                int x = t + c * 256;
                float If   = fmaf(2.f, Re4[c], -U0r);
                float Imax = If * (1.02f * 1.02f);
                out[0 * OS + obase + x] = sigm(50.f * (If   - 0.225f));
                out[2 * OS + obase + x] = sigm(50.f * (Imax - 0.225f));
                out[3 * OS + obase + x] = If;
                out[5 * OS + obase + x] = Imax;
            }
        } else {
            #pragma unroll
            for (int c = 0; c < 4; ++c) {
                int x = t + c * 256;
                float Id = fmaf(2.f, Re4[c], -U0r);
                out[1 * OS + obase + x] = sigm(50.f * (Id - 0.225f));
                out[4 * OS + obase + x] = Id;
            }
        }
    }
}

// ---- cooperative mega-kernel: 3 grid syncs replace 4 launch gaps ----
__global__ __launch_bounds__(TPB, 2) void mega(const float* __restrict__ mt,
    const float* __restrict__ kfr, const float* __restrict__ kfi,
    const float* __restrict__ kdr, const float* __restrict__ kdi,
    const float* __restrict__ kfs, const float* __restrict__ kds,
    float* __restrict__ out, float* __restrict__ ws)
{
    __shared__ SMem sm;
    cg::grid_group grid = cg::this_grid();
    int bid = blockIdx.x, t = threadIdx.x;
    gen_twl(sm, t);
    phase1(sm, mt, ws, bid, GRID, t);
    __threadfence(); grid.sync();
    phase2(sm, ws, bid, t);
    __threadfence(); grid.sync();
    phase3(sm, ws, kfr, kfi, kdr, kdi, kfs, kds, bid, GRID, t);
    __threadfence(); grid.sync();
    phase4(sm, ws, out, bid, t);
}

// ---- non-cooperative fallback wrappers (same device code) ----
__global__ __launch_bounds__(TPB, 2) void k_p1(const float* __restrict__ mt, float* __restrict__ ws) {
    __shared__ SMem sm;
    gen_twl(sm, threadIdx.x);
    phase1(sm, mt, ws, blockIdx.x, gridDim.x, threadIdx.x);
}
__global__ __launch_bounds__(TPB, 2) void k_p2(float* __restrict__ ws) {
    __shared__ SMem sm;
    gen_twl(sm, threadIdx.x);
    phase2(sm, ws, blockIdx.x, threadIdx.x);
}
__global__ __launch_bounds__(TPB, 2) void k_p3(float* __restrict__ ws,
        const float* __restrict__ kfr, const float* __restrict__ kfi,
        const float* __restrict__ kdr, const float* __restrict__ kdi,
        const float* __restrict__ kfs, const float* __restrict__ kds) {
    __shared__ SMem sm;
    phase3(sm, ws, kfr, kfi, kdr, kdi, kfs, kds, blockIdx.x, gridDim.x, threadIdx.x);
}
__global__ __launch_bounds__(TPB, 2) void k_p4(const float* __restrict__ ws, float* __restrict__ out) {
    __shared__ SMem sm;
    gen_twl(sm, threadIdx.x);
    phase4(sm, ws, out, blockIdx.x, threadIdx.x);
}

extern "C" void kernel_launch(void* const* d_in, const int* in_sizes, int n_in,
                              void* d_out, int out_size, void* d_ws, size_t ws_size,
                              hipStream_t stream) {
    (void)in_sizes; (void)n_in; (void)out_size; (void)ws_size;
    const float* mt  = (const float*)d_in[0];
    const float* kfr = (const float*)d_in[1];
    const float* kfi = (const float*)d_in[2];
    const float* kdr = (const float*)d_in[3];
    const float* kdi = (const float*)d_in[4];
    const float* kfs = (const float*)d_in[5];
    const float* kds = (const float*)d_in[6];
    float* out = (float*)d_out;
    float* ws  = (float*)d_ws;

    void* kargs[] = { (void*)&mt, (void*)&kfr, (void*)&kfi, (void*)&kdr, (void*)&kdi,
                      (void*)&kfs, (void*)&kds, (void*)&out, (void*)&ws };
    hipError_t err = hipLaunchCooperativeKernel((void*)mega, dim3(GRID), dim3(TPB),
                                                kargs, 0, stream);
    if (err != hipSuccess) {
        (void)hipGetLastError();   // clear; fall back to 4 plain launches
        hipLaunchKernelGGL(k_p1, dim3(GRID),          dim3(TPB), 0, stream, mt, ws);
        hipLaunchKernelGGL(k_p2, dim3(NBATCH * KDIM), dim3(TPB), 0, stream, ws);
        hipLaunchKernelGGL(k_p3, dim3(GRID),          dim3(TPB), 0, stream,
                           ws, kfr, kfi, kdr, kdi, kfs, kds);
        hipLaunchKernelGGL(k_p4, dim3(GRID),          dim3(TPB), 0, stream, ws, out);
    }
}

// Round 4
// 202.266 us; speedup vs baseline: 2.4094x; 2.4094x over previous
//
#include <hip/hip_runtime.h>
#include <math.h>

#define NBATCH 2
#define HH 1024
#define WW 1024
#define KKER 24
#define KDIM 35
#define NPIX (HH*WW)
#define KSQ (KDIM*KDIM)          // 1225
#define NDA 69                   // da in [-34,34]
#define NTAU 9                   // dai tiles of 8 (last has 5)
#define NFR 18                   // stored row freqs m=0..17 (Hermitian half)
#define VCOLS 43                 // X cols 0..34 valid, 35..42 zero pad

// ---- workspace layout (float offsets) ----
#define G_OFF 0                                  // [n][y][m] complex: 2*1024*18
#define S_OFF (G_OFF + NBATCH*HH*NFR*2)          // full-plane spec [n][a][b] complex
#define V_OFF (S_OFF + NBATCH*KSQ*2)             // [nb][dai][db] complex (atomic acc)
#define V_FLOATS (NBATCH*2*NDA*KDIM*2)           // 19320

__device__ __forceinline__ float2 cmadd(float2 p, float2 w, float2 u) {
    return make_float2(fmaf(p.x, w.x, fmaf(-p.y, w.y, u.x)),
                       fmaf(p.x, w.y, fmaf( p.y, w.x, u.y)));
}
__device__ __forceinline__ float sigm(float v) {
    return 1.f / (1.f + expf(-v));
}

// fused: avepool3(zero-pad) + sigmoid + forward DFT along x for m=0..17 (real input:
// G[n,y,-m] = conj(G[n,y,m]), so only half the freqs are computed/stored).
__global__ __launch_bounds__(320) void fwd_rows(const float* __restrict__ mt, float* __restrict__ ws) {
    __shared__ __align__(16) float vs[1024];
    __shared__ float row[1056];          // padded: idx = x + (x>>5) -> kills 4-way bank conflict
    __shared__ float2 twl[1024];
    __shared__ float2 P[16 * NFR];
    int bid = blockIdx.x;            // n*HH + y
    int n = bid >> 10, y = bid & 1023;
    int t = threadIdx.x;
    const float* base = mt + (size_t)n * NPIX;
    if (t < 256) {
        float4 a = ((const float4*)(base + (size_t)y * WW))[t];
        if (y > 0)    { float4 b = ((const float4*)(base + (size_t)(y - 1) * WW))[t];
                        a.x += b.x; a.y += b.y; a.z += b.z; a.w += b.w; }
        if (y < 1023) { float4 b = ((const float4*)(base + (size_t)(y + 1) * WW))[t];
                        a.x += b.x; a.y += b.y; a.z += b.z; a.w += b.w; }
        ((float4*)vs)[t] = a;
    }
    for (int j = t; j < 1024; j += 320) {
        float s, c;
        sincospif(-2.0f * (float)j * (1.0f / 1024.0f), &s, &c);
        twl[j] = make_float2(c, s);      // e^{-2 pi i j / 1024}
    }
    __syncthreads();
    for (int x = t; x < 1024; x += 320) {
        float s = vs[x];
        if (x > 0)    s += vs[x - 1];
        if (x < 1023) s += vs[x + 1];
        s *= (1.0f / 9.0f);
        row[x + (x >> 5)] = sigm(4.0f * (s - 0.5f));
    }
    __syncthreads();
    if (t < 16 * NFR) {
        int q = t / NFR, m = t - q * NFR;   // q in [0,16), m in [0,18)
        float2 cm = twl[m];                 // e^{-2pi i m/1024}
        float ar = 0.f, ai = 0.f;
        #pragma unroll
        for (int sc = 0; sc < 2; ++sc) {
            int xs = q * 64 + sc * 32;
            unsigned j0 = ((unsigned)(m * xs)) & 1023u;
            float2 wv = twl[j0];               // exact resync
            float wr = wv.x, wi = wv.y;
            int rb = xs + (xs >> 5);
            #pragma unroll
            for (int i = 0; i < 32; ++i) {
                float val = row[rb + i];
                ar = fmaf(val, wr, ar);
                ai = fmaf(val, wi, ai);
                float nwr = fmaf(wr, cm.x, -wi * cm.y);
                float nwi = fmaf(wr, cm.y,  wi * cm.x);
                wr = nwr; wi = nwi;
            }
        }
        P[t] = make_float2(ar, ai);
    }
    __syncthreads();
    if (t < NFR) {
        float gr = 0.f, gi = 0.f;
        #pragma unroll
        for (int q = 0; q < 16; ++q) {
            gr += P[q * NFR + t].x;
            gi += P[q * NFR + t].y;
        }
        float2* Gp = (float2*)(ws + G_OFF) + (size_t)(n * HH + y) * NFR + t;
        *Gp = make_float2(gr, gi);
    }
}

// forward DFT along y for half-plane b>=17, Hermitian-mirrored to full spec plane.
// 1024 threads (16 waves) per block to hide G-read latency; blocks 70..71 zero V
// for mk_V's atomic accumulation.
__global__ __launch_bounds__(1024) void fwd_cols(float* __restrict__ ws) {
    __shared__ float2 twl[1024];
    __shared__ float2 P[56 * NFR];
    int bid = blockIdx.x;            // n*KDIM + a   (or V-zero tail blocks)
    int t = threadIdx.x;
    if (bid >= NBATCH * KDIM) {
        int half = bid - NBATCH * KDIM;          // 0 or 1
        for (int i = half * (V_FLOATS / 2) + t; i < (half + 1) * (V_FLOATS / 2); i += 1024)
            ws[V_OFF + i] = 0.f;
        return;
    }
    int n = bid / KDIM, a = bid - n * KDIM;
    {
        float s, c;
        sincospif(-2.0f * (float)t * (1.0f / 1024.0f), &s, &c);
        twl[t] = make_float2(c, s);
    }
    __syncthreads();
    if (t < 56 * NFR) {
        int g = t / NFR, mb = t - NFR * g;       // g in [0,56) y-chunks, mb = b-17
        int ys = (g << 10) / 56, ye = ((g + 1) << 10) / 56;
        int ma = a - 17;
        const float2* Gp = (const float2*)(ws + G_OFF) + (size_t)n * HH * NFR + mb;
        float ar = 0.f, ai = 0.f;
        for (int y = ys; y < ye; ++y) {
            float2 g2 = Gp[(size_t)y * NFR];
            float2 cc = twl[((unsigned)(ma * y)) & 1023u];
            ar = fmaf(g2.x, cc.x, ar); ar = fmaf(-g2.y, cc.y, ar);
            ai = fmaf(g2.x, cc.y, ai); ai = fmaf( g2.y, cc.x, ai);
        }
        P[t] = make_float2(ar, ai);
    }
    __syncthreads();
    if (t < NFR) {
        float sr = 0.f, si = 0.f;
        #pragma unroll
        for (int g = 0; g < 56; ++g) { sr += P[g * NFR + t].x; si += P[g * NFR + t].y; }
        float2* Sp = (float2*)(ws + S_OFF) + (size_t)n * KSQ;
        Sp[a * KDIM + (17 + t)] = make_float2(sr, si);
        if (t > 0)
            Sp[(34 - a) * KDIM + (17 - t)] = make_float2(sr, -si);  // Hermitian mirror
    }
}

// 2D autocorrelation V[da,db] = sum_{ap,bp} X[ap+da, bp+db] * conj(X[ap,bp]).
// Blocks tile dai into NTAU tiles of 8 (valid ap-overlap window only). 8 waves per
// block; since V is accumulated with atomics, waves split the (db-octet, bp-range)
// space into near-equal chunks (max 14 bp-units vs 35 unsplit):
//   w0-2: oct0 bp[0,12)[12,24)[24,35) | w3-4: oct1 [0,13)[13,27)
//   w5-6: oct2 [0,9)[9,19)            | w7:   oct3 [0,11) + oct4 [0,3)
// Lane = (dai8, apSlot); exec-mask for ap+da validity; shfl_xor reduce over apSlots.
__global__ __launch_bounds__(512) void mk_V(float* __restrict__ ws,
        const float* __restrict__ kfr, const float* __restrict__ kfi,
        const float* __restrict__ kdr, const float* __restrict__ kdi,
        const float* __restrict__ kfs, const float* __restrict__ kds) {
    __shared__ float2 Xp[KDIM * VCOLS];   // 12 KB
    int bid = blockIdx.x;
    int tau = bid % NTAU; int r = bid / NTAU;
    int k = r % KKER; r /= KKER;
    int br = r & 1; int n = r >> 1;
    int t = threadIdx.x;
    for (int i = t; i < KDIM * VCOLS; i += 512) Xp[i] = make_float2(0.f, 0.f);
    __syncthreads();
    const float* kr = (br ? kdr : kfr) + (size_t)k * KSQ;
    const float* ki = (br ? kdi : kfi) + (size_t)k * KSQ;
    const float* sp = ws + S_OFF + (size_t)n * KSQ * 2;
    for (int i = t; i < KSQ; i += 512) {
        int a = i / KDIM, b = i - a * KDIM;
        float srr = sp[2*i], sii = sp[2*i + 1];
        float krr = kr[i], kii = ki[i];
        Xp[a * VCOLS + b] = make_float2(srr * krr - sii * kii, srr * kii + sii * krr);
    }
    __syncthreads();
    float s = (br ? kds[k] * (0.98f * 0.98f) : kfs[k]) * 0x1p-40f;

    int wv = t >> 6, lane = t & 63;
    int apSlot = lane & 7, dai8 = lane >> 3;
    int dai = tau * 8 + dai8, da = dai - 34;
    int daiHi = tau * 8 + 7; if (daiHi > NDA - 1) daiHi = NDA - 1;
    int apLo = -(daiHi - 34); if (apLo < 0) apLo = 0;
    int apHi = KDIM - (tau * 8 - 34); if (apHi > KDIM) apHi = KDIM;
    bool lv = (dai < NDA);

    const int octTab[8] = {0, 0, 0, 1, 1, 2, 2, 3};
    const int b0Tab[8]  = {0, 12, 24, 0, 13, 0, 9, 0};
    const int b1Tab[8]  = {12, 24, 35, 13, 27, 9, 19, 11};
    int npass = (wv == 7) ? 2 : 1;
    for (int p = 0; p < npass; ++p) {
        int db0 = p ? 32 : octTab[wv] * 8;
        int b0  = p ? 0  : b0Tab[wv];
        int b1  = p ? 3  : b1Tab[wv];
        float2 acc[8];
        #pragma unroll
        for (int j = 0; j < 8; ++j) acc[j] = make_float2(0.f, 0.f);
        for (int ap = apLo + apSlot; ap < apHi; ap += 8) {
            if (lv && ((unsigned)(ap + da) < (unsigned)KDIM)) {
                const float2* rx = Xp + (ap + da) * VCOLS + db0;
                const float2* ry = Xp + ap * VCOLS;
                float2 w[8];
                #pragma unroll
                for (int j = 0; j < 8; ++j) w[j] = rx[b0 + j];
                int bp = b0;
                for (; bp + 8 <= b1; bp += 8) {
                    #pragma unroll
                    for (int u = 0; u < 8; ++u) {
                        float2 yv = ry[bp + u];
                        #pragma unroll
                        for (int j = 0; j < 8; ++j) {
                            acc[j].x = fmaf(w[j].x, yv.x, acc[j].x);
                            acc[j].x = fmaf(w[j].y, yv.y, acc[j].x);
                            acc[j].y = fmaf(w[j].y, yv.x, acc[j].y);
                            acc[j].y = fmaf(-w[j].x, yv.y, acc[j].y);
                        }
                        #pragma unroll
                        for (int j = 0; j < 7; ++j) w[j] = w[j + 1];
                        w[7] = rx[bp + u + 8];
                    }
                }
                for (; bp < b1; ++bp) {
                    float2 yv = ry[bp];
                    #pragma unroll
                    for (int j = 0; j < 8; ++j) {
                        acc[j].x = fmaf(w[j].x, yv.x, acc[j].x);
                        acc[j].x = fmaf(w[j].y, yv.y, acc[j].x);
                        acc[j].y = fmaf(w[j].y, yv.x, acc[j].y);
                        acc[j].y = fmaf(-w[j].x, yv.y, acc[j].y);
                    }
                    #pragma unroll
                    for (int j = 0; j < 7; ++j) w[j] = w[j + 1];
                    w[7] = rx[bp + 8];
                }
            }
        }
        #pragma unroll
        for (int j = 0; j < 8; ++j) {             // reduce the 8 apSlot partials
            acc[j].x += __shfl_xor(acc[j].x, 1); acc[j].y += __shfl_xor(acc[j].y, 1);
            acc[j].x += __shfl_xor(acc[j].x, 2); acc[j].y += __shfl_xor(acc[j].y, 2);
            acc[j].x += __shfl_xor(acc[j].x, 4); acc[j].y += __shfl_xor(acc[j].y, 4);
        }
        if (apSlot == 0 && lv) {
            int nb = n * 2 + br;
            float* vb = ws + V_OFF + (((size_t)nb * NDA + dai) * KDIM + db0) * 2;
            #pragma unroll
            for (int j = 0; j < 8; ++j) if (db0 + j < KDIM) {
                atomicAdd(vb + 2 * j,     s * acc[j].x);
                atomicAdd(vb + 2 * j + 1, s * acc[j].y);
            }
        }
    }
}

// Fused mk_U + radix-4 epilogue. Block = (nb, yc); handles YPB consecutive y rows:
//   U[y,db] = sum_dai V[nb][dai][db] e^{+2pi i y (dai-34)/1024}   (computed in LDS)
//   then per row, thread t evaluates x = t+256c via S(i^c z) from four 9-term
//   Horner chains in w=z^4. I = 2*Re(S) - U0r (Hermitian half along x).
#define YPB 2
__global__ __launch_bounds__(256) void litho_fused(const float* __restrict__ ws,
                                                   float* __restrict__ out) {
    __shared__ float2 twl[1024];
    __shared__ float2 Vl[NDA * KDIM];
    __shared__ float2 Ul[YPB][KDIM];
    int bid = blockIdx.x;              // nb*512 + yc
    int yc = bid & 511; int nb = bid >> 9;
    int t = threadIdx.x;
    for (int j = t; j < 1024; j += 256) {
        float s, c;
        sincospif(-2.0f * (float)j * (1.0f / 1024.0f), &s, &c);
        twl[j] = make_float2(c, s);
    }
    const float2* Vg = (const float2*)(ws + V_OFF) + (size_t)nb * NDA * KDIM;
    for (int i = t; i < NDA * KDIM; i += 256) Vl[i] = Vg[i];
    __syncthreads();
    if (t < YPB * KDIM) {
        int yl = t / KDIM, db = t - yl * KDIM;
        int y = yc * YPB + yl;
        float ar = 0.f, ai = 0.f;
        for (int dai = 0; dai < NDA; ++dai) {
            float2 cc = twl[((unsigned)(y * (dai - 34))) & 1023u];
            float cr = cc.x, ci = -cc.y;           // e^{+2pi i y da/1024}
            float2 v = Vl[dai * KDIM + db];
            ar = fmaf(v.x, cr, ar); ar = fmaf(-v.y, ci, ar);
            ai = fmaf(v.x, ci, ai); ai = fmaf( v.y, cr, ai);
        }
        Ul[yl][db] = make_float2(ar, ai);
    }
    __syncthreads();
    int n = nb >> 1, br = nb & 1;
    float2 z  = twl[t];              z.y  = -z.y;    // e^{+2pi i t/1024}
    float2 z2 = twl[(2*t) & 1023];   z2.y = -z2.y;
    float2 z3 = twl[(3*t) & 1023];   z3.y = -z3.y;
    float2 w  = twl[(4*t) & 1023];   w.y  = -w.y;    // z^4
    const size_t OS = (size_t)NBATCH * NPIX;
    #pragma unroll
    for (int yl = 0; yl < YPB; ++yl) {
        int y = yc * YPB + yl;
        float2 P0 = Ul[yl][32], P1 = Ul[yl][33], P2 = Ul[yl][34], P3 = make_float2(0.f, 0.f);
        #pragma unroll
        for (int q = 7; q >= 0; --q) {
            P0 = cmadd(P0, w, Ul[yl][4*q]);
            P1 = cmadd(P1, w, Ul[yl][4*q+1]);
            P2 = cmadd(P2, w, Ul[yl][4*q+2]);
            P3 = cmadd(P3, w, Ul[yl][4*q+3]);
        }
        float U0r = Ul[yl][0].x;
        float A1x = P1.x * z.x  - P1.y * z.y,  A1y = P1.x * z.y  + P1.y * z.x;
        float A2x = P2.x * z2.x - P2.y * z2.y;
        float A3x = P3.x * z3.x - P3.y * z3.y, A3y = P3.x * z3.y + P3.y * z3.x;
        float Re4[4];
        Re4[0] = P0.x + A1x + A2x + A3x;
        Re4[1] = P0.x - A1y - A2x + A3y;
        Re4[2] = P0.x - A1x + A2x - A3x;
        Re4[3] = P0.x + A1y - A2x - A3y;
        size_t obase = (size_t)n * NPIX + (size_t)y * WW;
        if (br == 0) {
            #pragma unroll
            for (int c = 0; c < 4; ++c) {
                int x = t + c * 256;
                float If   = fmaf(2.f, Re4[c], -U0r);
                float Imax = If * (1.02f * 1.02f);
                out[0 * OS + obase + x] = sigm(50.f * (If   - 0.225f));
                out[2 * OS + obase + x] = sigm(50.f * (Imax - 0.225f));
                out[3 * OS + obase + x] = If;
                out[5 * OS + obase + x] = Imax;
            }
        } else {
            #pragma unroll
            for (int c = 0; c < 4; ++c) {
                int x = t + c * 256;
                float Id = fmaf(2.f, Re4[c], -U0r);
                out[1 * OS + obase + x] = sigm(50.f * (Id - 0.225f));
                out[4 * OS + obase + x] = Id;
            }
        }
    }
}

extern "C" void kernel_launch(void* const* d_in, const int* in_sizes, int n_in,
                              void* d_out, int out_size, void* d_ws, size_t ws_size,
                              hipStream_t stream) {
    (void)in_sizes; (void)n_in; (void)out_size; (void)ws_size;
    const float* mt  = (const float*)d_in[0];
    const float* kfr = (const float*)d_in[1];
    const float* kfi = (const float*)d_in[2];
    const float* kdr = (const float*)d_in[3];
    const float* kdi = (const float*)d_in[4];
    const float* kfs = (const float*)d_in[5];
    const float* kds = (const float*)d_in[6];
    float* out = (float*)d_out;
    float* ws  = (float*)d_ws;

    hipLaunchKernelGGL(fwd_rows,    dim3(NBATCH * HH),              dim3(320),  0, stream, mt, ws);
    hipLaunchKernelGGL(fwd_cols,    dim3(NBATCH * KDIM + 2),        dim3(1024), 0, stream, ws);
    hipLaunchKernelGGL(mk_V,        dim3(NBATCH * 2 * KKER * NTAU), dim3(512),  0, stream,
                       ws, kfr, kfi, kdr, kdi, kfs, kds);
    hipLaunchKernelGGL(litho_fused, dim3(NBATCH * 2 * 512),         dim3(256),  0, stream, ws, out);
}

// Round 5
// 154.914 us; speedup vs baseline: 3.1459x; 1.3057x over previous
//
#include <hip/hip_runtime.h>
#include <math.h>

#define NBATCH 2
#define HH 1024
#define WW 1024
#define KKER 24
#define KDIM 35
#define NPIX (HH*WW)
#define KSQ (KDIM*KDIM)          // 1225
#define NDA 69                   // da in [-34,34]
#define NTAU 9                   // dai tiles of 8 (last has 5)
#define NFR 18                   // stored row freqs m=0..17 (Hermitian half)
#define VCOLS 43                 // X cols 0..34 valid, 35..42 zero pad

// ---- workspace layout (float offsets) ----
#define G_OFF 0                                  // [n][y][m] complex: 2*1024*18
#define S_OFF (G_OFF + NBATCH*HH*NFR*2)          // full-plane spec [n][a][b] complex
#define VP_OFF (S_OFF + NBATCH*KSQ*2)            // [nb][k][dai][db] complex partials
#define V_OFF (VP_OFF + NBATCH*2*KKER*NDA*KDIM*2)// [nb][dai][db] complex

__device__ __forceinline__ float2 cmadd(float2 p, float2 w, float2 u) {
    return make_float2(fmaf(p.x, w.x, fmaf(-p.y, w.y, u.x)),
                       fmaf(p.x, w.y, fmaf( p.y, w.x, u.y)));
}
__device__ __forceinline__ float sigm(float v) {
    return 1.f / (1.f + expf(-v));
}

// fused: avepool3(zero-pad) + sigmoid + forward DFT along x for m=0..17 (real input:
// G[n,y,-m] = conj(G[n,y,m]), so only half the freqs are computed/stored).
__global__ __launch_bounds__(320) void fwd_rows(const float* __restrict__ mt, float* __restrict__ ws) {
    __shared__ __align__(16) float vs[1024];
    __shared__ float row[1056];          // padded: idx = x + (x>>5) -> kills 4-way bank conflict
    __shared__ float2 twl[1024];
    __shared__ float2 P[16 * NFR];
    int bid = blockIdx.x;            // n*HH + y
    int n = bid >> 10, y = bid & 1023;
    int t = threadIdx.x;
    const float* base = mt + (size_t)n * NPIX;
    if (t < 256) {
        float4 a = ((const float4*)(base + (size_t)y * WW))[t];
        if (y > 0)    { float4 b = ((const float4*)(base + (size_t)(y - 1) * WW))[t];
                        a.x += b.x; a.y += b.y; a.z += b.z; a.w += b.w; }
        if (y < 1023) { float4 b = ((const float4*)(base + (size_t)(y + 1) * WW))[t];
                        a.x += b.x; a.y += b.y; a.z += b.z; a.w += b.w; }
        ((float4*)vs)[t] = a;
    }
    for (int j = t; j < 1024; j += 320) {
        float s, c;
        sincospif(-2.0f * (float)j * (1.0f / 1024.0f), &s, &c);
        twl[j] = make_float2(c, s);      // e^{-2 pi i j / 1024}
    }
    __syncthreads();
    for (int x = t; x < 1024; x += 320) {
        float s = vs[x];
        if (x > 0)    s += vs[x - 1];
        if (x < 1023) s += vs[x + 1];
        s *= (1.0f / 9.0f);
        row[x + (x >> 5)] = sigm(4.0f * (s - 0.5f));
    }
    __syncthreads();
    if (t < 16 * NFR) {
        int q = t / NFR, m = t - q * NFR;   // q in [0,16), m in [0,18)
        float2 cm = twl[m];                 // e^{-2pi i m/1024}
        float ar = 0.f, ai = 0.f;
        #pragma unroll
        for (int sc = 0; sc < 2; ++sc) {
            int xs = q * 64 + sc * 32;
            unsigned j0 = ((unsigned)(m * xs)) & 1023u;
            float2 wv = twl[j0];               // exact resync
            float wr = wv.x, wi = wv.y;
            int rb = xs + (xs >> 5);
            #pragma unroll
            for (int i = 0; i < 32; ++i) {
                float val = row[rb + i];
                ar = fmaf(val, wr, ar);
                ai = fmaf(val, wi, ai);
                float nwr = fmaf(wr, cm.x, -wi * cm.y);
                float nwi = fmaf(wr, cm.y,  wi * cm.x);
                wr = nwr; wi = nwi;
            }
        }
        P[t] = make_float2(ar, ai);
    }
    __syncthreads();
    if (t < NFR) {
        float gr = 0.f, gi = 0.f;
        #pragma unroll
        for (int q = 0; q < 16; ++q) {
            gr += P[q * NFR + t].x;
            gi += P[q * NFR + t].y;
        }
        float2* Gp = (float2*)(ws + G_OFF) + (size_t)(n * HH + y) * NFR + t;
        *Gp = make_float2(gr, gi);
    }
}

// forward DFT along y for half-plane b>=17, Hermitian-mirrored to full spec plane.
// 1024 threads (16 waves) per block to hide G-read latency.
__global__ __launch_bounds__(1024) void fwd_cols(float* __restrict__ ws) {
    __shared__ float2 twl[1024];
    __shared__ float2 P[56 * NFR];
    int bid = blockIdx.x;            // n*KDIM + a
    int t = threadIdx.x;
    int n = bid / KDIM, a = bid - n * KDIM;
    {
        float s, c;
        sincospif(-2.0f * (float)t * (1.0f / 1024.0f), &s, &c);
        twl[t] = make_float2(c, s);
    }
    __syncthreads();
    if (t < 56 * NFR) {
        int g = t / NFR, mb = t - NFR * g;       // g in [0,56) y-chunks, mb = b-17
        int ys = (g << 10) / 56, ye = ((g + 1) << 10) / 56;
        int ma = a - 17;
        const float2* Gp = (const float2*)(ws + G_OFF) + (size_t)n * HH * NFR + mb;
        float ar = 0.f, ai = 0.f;
        for (int y = ys; y < ye; ++y) {
            float2 g2 = Gp[(size_t)y * NFR];
            float2 cc = twl[((unsigned)(ma * y)) & 1023u];
            ar = fmaf(g2.x, cc.x, ar); ar = fmaf(-g2.y, cc.y, ar);
            ai = fmaf(g2.x, cc.y, ai); ai = fmaf( g2.y, cc.x, ai);
        }
        P[t] = make_float2(ar, ai);
    }
    __syncthreads();
    if (t < NFR) {
        float sr = 0.f, si = 0.f;
        #pragma unroll
        for (int g = 0; g < 56; ++g) { sr += P[g * NFR + t].x; si += P[g * NFR + t].y; }
        float2* Sp = (float2*)(ws + S_OFF) + (size_t)n * KSQ;
        Sp[a * KDIM + (17 + t)] = make_float2(sr, si);
        if (t > 0)
            Sp[(34 - a) * KDIM + (17 - t)] = make_float2(sr, -si);  // Hermitian mirror
    }
}

// 2D autocorrelation V[da,db] = sum_{ap,bp} X[ap+da, bp+db] * conj(X[ap,bp]).
// Blocks tile dai into NTAU tiles of 8 (valid ap-overlap window only). 8 waves per
// block split the (db-octet, bp-range) space into near-equal chunks (max 14 bp-units
// vs 35 unsplit). Each wave-pass writes its partial (8 dai x 8 db) tile to a PRIVATE
// LDS slot Vp[pass]; after a barrier, 280 threads sum the 1..3 slots per octet and
// do ONE plain global store per element (no atomics -> no cross-XCD RMW traffic).
//   pass/oct/bp table: w0-2: oct0 [0,12)[12,24)[24,35) | w3-4: oct1 [0,13)[13,27)
//                      w5-6: oct2 [0,9)[9,19)          | w7: oct3 [0,11) + oct4 [0,3)
__global__ __launch_bounds__(512) void mk_V(float* __restrict__ ws,
        const float* __restrict__ kfr, const float* __restrict__ kfi,
        const float* __restrict__ kdr, const float* __restrict__ kdi,
        const float* __restrict__ kfs, const float* __restrict__ kds) {
    __shared__ float2 Xp[KDIM * VCOLS];   // 12 KB
    __shared__ float2 Vp[9][8][8];        // 4.6 KB: per-pass partial tiles
    int bid = blockIdx.x;
    int tau = bid % NTAU; int r = bid / NTAU;
    int k = r % KKER; r /= KKER;
    int br = r & 1; int n = r >> 1;
    int t = threadIdx.x;
    for (int i = t; i < KDIM * VCOLS; i += 512) Xp[i] = make_float2(0.f, 0.f);
    __syncthreads();
    const float* kr = (br ? kdr : kfr) + (size_t)k * KSQ;
    const float* ki = (br ? kdi : kfi) + (size_t)k * KSQ;
    const float* sp = ws + S_OFF + (size_t)n * KSQ * 2;
    for (int i = t; i < KSQ; i += 512) {
        int a = i / KDIM, b = i - a * KDIM;
        float srr = sp[2*i], sii = sp[2*i + 1];
        float krr = kr[i], kii = ki[i];
        Xp[a * VCOLS + b] = make_float2(srr * krr - sii * kii, srr * kii + sii * krr);
    }
    __syncthreads();

    int wv = t >> 6, lane = t & 63;
    int apSlot = lane & 7, dai8 = lane >> 3;
    int dai = tau * 8 + dai8, da = dai - 34;
    int daiHi = tau * 8 + 7; if (daiHi > NDA - 1) daiHi = NDA - 1;
    int apLo = -(daiHi - 34); if (apLo < 0) apLo = 0;
    int apHi = KDIM - (tau * 8 - 34); if (apHi > KDIM) apHi = KDIM;
    bool lv = (dai < NDA);

    // wave -> (oct, bp-range) via uniform scalar selects (no runtime-indexed array)
    int oct = (wv < 3) ? 0 : (wv < 5) ? 1 : (wv < 7) ? 2 : 3;
    int b0w = (wv == 1) ? 12 : (wv == 2) ? 24 : (wv == 4) ? 13 : (wv == 6) ? 9 : 0;
    int b1w = (wv == 0) ? 12 : (wv == 1) ? 24 : (wv == 2) ? 35 :
              (wv == 3) ? 13 : (wv == 4) ? 27 : (wv == 5) ? 9  :
              (wv == 6) ? 19 : 11;
    int npass = (wv == 7) ? 2 : 1;
    for (int p = 0; p < npass; ++p) {
        int db0 = p ? 32 : oct * 8;
        int b0  = p ? 0  : b0w;
        int b1  = p ? 3  : b1w;
        int slot = p ? 8 : wv;
        float2 acc[8];
        #pragma unroll
        for (int j = 0; j < 8; ++j) acc[j] = make_float2(0.f, 0.f);
        for (int ap = apLo + apSlot; ap < apHi; ap += 8) {
            if (lv && ((unsigned)(ap + da) < (unsigned)KDIM)) {
                const float2* rx = Xp + (ap + da) * VCOLS + db0;
                const float2* ry = Xp + ap * VCOLS;
                float2 w[8];
                #pragma unroll
                for (int j = 0; j < 8; ++j) w[j] = rx[b0 + j];
                int bp = b0;
                for (; bp + 8 <= b1; bp += 8) {
                    #pragma unroll
                    for (int u = 0; u < 8; ++u) {
                        float2 yv = ry[bp + u];
                        #pragma unroll
                        for (int j = 0; j < 8; ++j) {
                            acc[j].x = fmaf(w[j].x, yv.x, acc[j].x);
                            acc[j].x = fmaf(w[j].y, yv.y, acc[j].x);
                            acc[j].y = fmaf(w[j].y, yv.x, acc[j].y);
                            acc[j].y = fmaf(-w[j].x, yv.y, acc[j].y);
                        }
                        #pragma unroll
                        for (int j = 0; j < 7; ++j) w[j] = w[j + 1];
                        w[7] = rx[bp + u + 8];
                    }
                }
                for (; bp < b1; ++bp) {
                    float2 yv = ry[bp];
                    #pragma unroll
                    for (int j = 0; j < 8; ++j) {
                        acc[j].x = fmaf(w[j].x, yv.x, acc[j].x);
                        acc[j].x = fmaf(w[j].y, yv.y, acc[j].x);
                        acc[j].y = fmaf(w[j].y, yv.x, acc[j].y);
                        acc[j].y = fmaf(-w[j].x, yv.y, acc[j].y);
                    }
                    #pragma unroll
                    for (int j = 0; j < 7; ++j) w[j] = w[j + 1];
                    w[7] = rx[bp + 8];
                }
            }
        }
        #pragma unroll
        for (int j = 0; j < 8; ++j) {             // reduce the 8 apSlot partials
            acc[j].x += __shfl_xor(acc[j].x, 1); acc[j].y += __shfl_xor(acc[j].y, 1);
            acc[j].x += __shfl_xor(acc[j].x, 2); acc[j].y += __shfl_xor(acc[j].y, 2);
            acc[j].x += __shfl_xor(acc[j].x, 4); acc[j].y += __shfl_xor(acc[j].y, 4);
        }
        if (apSlot == 0) {
            #pragma unroll
            for (int j = 0; j < 8; ++j) Vp[slot][dai8][j] = acc[j];
        }
    }
    __syncthreads();
    // sum the per-pass slots and store VP[nb][k][dai][db] (plain stores, no atomics)
    if (t < 8 * KDIM) {
        int d8 = t / KDIM, db = t - d8 * KDIM;
        int dai2 = tau * 8 + d8;
        if (dai2 < NDA) {
            int oc = db >> 3, j = db & 7;
            float2 sum;
            if (oc == 0) {
                sum = make_float2(Vp[0][d8][j].x + Vp[1][d8][j].x + Vp[2][d8][j].x,
                                  Vp[0][d8][j].y + Vp[1][d8][j].y + Vp[2][d8][j].y);
            } else if (oc == 1) {
                sum = make_float2(Vp[3][d8][j].x + Vp[4][d8][j].x,
                                  Vp[3][d8][j].y + Vp[4][d8][j].y);
            } else if (oc == 2) {
                sum = make_float2(Vp[5][d8][j].x + Vp[6][d8][j].x,
                                  Vp[5][d8][j].y + Vp[6][d8][j].y);
            } else if (oc == 3) {
                sum = Vp[7][d8][j];
            } else {
                sum = Vp[8][d8][j];
            }
            float s = (br ? kds[k] * (0.98f * 0.98f) : kfs[k]) * 0x1p-40f;
            int nb = n * 2 + br;
            ((float2*)(ws + VP_OFF))[(((size_t)nb * KKER + k) * NDA + dai2) * KDIM + db] =
                make_float2(s * sum.x, s * sum.y);
        }
    }
}

// V[nb][dai][db] = sum_k VP[nb][k][dai][db]; one block per (nb,dai)
__global__ __launch_bounds__(64) void reduce_V(float* __restrict__ ws) {
    int bid = blockIdx.x;            // nb*NDA + dai
    int nb = bid / NDA, dai = bid - nb * NDA;
    int t = threadIdx.x;
    if (t < KDIM) {
        const float2* vp = (const float2*)(ws + VP_OFF);
        float sr = 0.f, si = 0.f;
        #pragma unroll
        for (int k = 0; k < KKER; ++k) {
            float2 v = vp[(((size_t)nb * KKER + k) * NDA + dai) * KDIM + t];
            sr += v.x; si += v.y;
        }
        ((float2*)(ws + V_OFF))[((size_t)nb * NDA + dai) * KDIM + t] = make_float2(sr, si);
    }
}

// Fused mk_U + radix-4 epilogue. Block = (nb, yc); handles YPB consecutive y rows:
//   U[y,db] = sum_dai V[nb][dai][db] e^{+2pi i y (dai-34)/1024}   (computed in LDS)
//   then per row, thread t evaluates x = t+256c via S(i^c z) from four 9-term
//   Horner chains in w=z^4. I = 2*Re(S) - U0r (Hermitian half along x).
#define YPB 2
__global__ __launch_bounds__(256) void litho_fused(const float* __restrict__ ws,
                                                   float* __restrict__ out) {
    __shared__ float2 twl[1024];
    __shared__ float2 Vl[NDA * KDIM];
    __shared__ float2 Ul[YPB][KDIM];
    int bid = blockIdx.x;              // nb*512 + yc
    int yc = bid & 511; int nb = bid >> 9;
    int t = threadIdx.x;
    for (int j = t; j < 1024; j += 256) {
        float s, c;
        sincospif(-2.0f * (float)j * (1.0f / 1024.0f), &s, &c);
        twl[j] = make_float2(c, s);
    }
    const float2* Vg = (const float2*)(ws + V_OFF) + (size_t)nb * NDA * KDIM;
    for (int i = t; i < NDA * KDIM; i += 256) Vl[i] = Vg[i];
    __syncthreads();
    if (t < YPB * KDIM) {
        int yl = t / KDIM, db = t - yl * KDIM;
        int y = yc * YPB + yl;
        float ar = 0.f, ai = 0.f;
        for (int dai = 0; dai < NDA; ++dai) {
            float2 cc = twl[((unsigned)(y * (dai - 34))) & 1023u];
            float cr = cc.x, ci = -cc.y;           // e^{+2pi i y da/1024}
            float2 v = Vl[dai * KDIM + db];
            ar = fmaf(v.x, cr, ar); ar = fmaf(-v.y, ci, ar);
            ai = fmaf(v.x, ci, ai); ai = fmaf( v.y, cr, ai);
        }
        Ul[yl][db] = make_float2(ar, ai);
    }
    __syncthreads();
    int n = nb >> 1, br = nb & 1;
    float2 z  = twl[t];              z.y  = -z.y;    // e^{+2pi i t/1024}
    float2 z2 = twl[(2*t) & 1023];   z2.y = -z2.y;
    float2 z3 = twl[(3*t) & 1023];   z3.y = -z3.y;
    float2 w  = twl[(4*t) & 1023];   w.y  = -w.y;    // z^4
    const size_t OS = (size_t)NBATCH * NPIX;
    #pragma unroll
    for (int yl = 0; yl < YPB; ++yl) {
        int y = yc * YPB + yl;
        float2 P0 = Ul[yl][32], P1 = Ul[yl][33], P2 = Ul[yl][34], P3 = make_float2(0.f, 0.f);
        #pragma unroll
        for (int q = 7; q >= 0; --q) {
            P0 = cmadd(P0, w, Ul[yl][4*q]);
            P1 = cmadd(P1, w, Ul[yl][4*q+1]);
            P2 = cmadd(P2, w, Ul[yl][4*q+2]);
            P3 = cmadd(P3, w, Ul[yl][4*q+3]);
        }
        float U0r = Ul[yl][0].x;
        float A1x = P1.x * z.x  - P1.y * z.y,  A1y = P1.x * z.y  + P1.y * z.x;
        float A2x = P2.x * z2.x - P2.y * z2.y;
        float A3x = P3.x * z3.x - P3.y * z3.y, A3y = P3.x * z3.y + P3.y * z3.x;
        float Re4[4];
        Re4[0] = P0.x + A1x + A2x + A3x;
        Re4[1] = P0.x - A1y - A2x + A3y;
        Re4[2] = P0.x - A1x + A2x - A3x;
        Re4[3] = P0.x + A1y - A2x - A3y;
        size_t obase = (size_t)n * NPIX + (size_t)y * WW;
        if (br == 0) {
            #pragma unroll
            for (int c = 0; c < 4; ++c) {
                int x = t + c * 256;
                float If   = fmaf(2.f, Re4[c], -U0r);
                float Imax = If * (1.02f * 1.02f);
                out[0 * OS + obase + x] = sigm(50.f * (If   - 0.225f));
                out[2 * OS + obase + x] = sigm(50.f * (Imax - 0.225f));
                out[3 * OS + obase + x] = If;
                out[5 * OS + obase + x] = Imax;
            }
        } else {
            #pragma unroll
            for (int c = 0; c < 4; ++c) {
                int x = t + c * 256;
                float Id = fmaf(2.f, Re4[c], -U0r);
                out[1 * OS + obase + x] = sigm(50.f * (Id - 0.225f));
                out[4 * OS + obase + x] = Id;
            }
        }
    }
}

extern "C" void kernel_launch(void* const* d_in, const int* in_sizes, int n_in,
                              void* d_out, int out_size, void* d_ws, size_t ws_size,
                              hipStream_t stream) {
    (void)in_sizes; (void)n_in; (void)out_size; (void)ws_size;
    const float* mt  = (const float*)d_in[0];
    const float* kfr = (const float*)d_in[1];
    const float* kfi = (const float*)d_in[2];
    const float* kdr = (const float*)d_in[3];
    const float* kdi = (const float*)d_in[4];
    const float* kfs = (const float*)d_in[5];
    const float* kds = (const float*)d_in[6];
    float* out = (float*)d_out;
    float* ws  = (float*)d_ws;

    hipLaunchKernelGGL(fwd_rows,    dim3(NBATCH * HH),              dim3(320),  0, stream, mt, ws);
    hipLaunchKernelGGL(fwd_cols,    dim3(NBATCH * KDIM),            dim3(1024), 0, stream, ws);
    hipLaunchKernelGGL(mk_V,        dim3(NBATCH * 2 * KKER * NTAU), dim3(512),  0, stream,
                       ws, kfr, kfi, kdr, kdi, kfs, kds);
    hipLaunchKernelGGL(reduce_V,    dim3(NBATCH * 2 * NDA),         dim3(64),   0, stream, ws);
    hipLaunchKernelGGL(litho_fused, dim3(NBATCH * 2 * 512),         dim3(256),  0, stream, ws, out);
}